// Round 1
// baseline (9786.449 us; speedup 1.0000x reference)
//
// Chunked parallel linear-RNN scan for MI355X (gfx950), bf16x3 split MFMA.
//   proj = x @ w_ih^T + b_ih                      (gemm3, K=128)
//   h_t  = h_{t-1} @ w_hh^T + proj[t-1]           (chunked scan)
// Phases: prep/split -> proj GEMM -> W^L squaring chain -> per-chunk local
// scans (phase B) -> boundary scan with software grid barrier (phase C) ->
// per-chunk emit scans writing both output copies (phase D).
// Scratch: proj in out-copy-2, x-splits/powers/e in out-copy-1 (dead before
// phase D); d_ws holds W-pack (4MB) + Z chunk inits (32MB) + barrier counters.

#include <hip/hip_runtime.h>
#include <stdint.h>

typedef unsigned int u32;
typedef unsigned short u16;
typedef __attribute__((ext_vector_type(4))) float f32x4;
typedef __attribute__((ext_vector_type(8))) short s16x8;
typedef __attribute__((ext_vector_type(4))) short s16x4;

#define NB 128
#define TS 2048
#define ID 128
#define HD 1024
#define LCH 32
#define CCH 64
#define NJT 64  // HD/16

__device__ __forceinline__ u16 f2bf(float f) {
  u32 u = __builtin_bit_cast(u32, f);
  u += 0x7FFFu + ((u >> 16) & 1u);
  return (u16)(u >> 16);
}
__device__ __forceinline__ float bf2f(u16 h) {
  u32 u = ((u32)h) << 16;
  return __builtin_bit_cast(float, u);
}
__device__ __forceinline__ void split2(float f, u16& hi, u16& lo) {
  hi = f2bf(f);
  lo = f2bf(f - bf2f(hi));
}
#define MFMA16(a, b, c) __builtin_amdgcn_mfma_f32_16x16x32_bf16((a), (b), (c), 0, 0, 0)

// XOR swizzle of fp32 state LDS [32][1024]: spreads 16-B groups across banks.
__device__ __forceinline__ int swz(int row, int col) {
  return row * HD + ((((col >> 2) ^ (row & 7)) << 2) | (col & 3));
}

// ---------------- prep kernels ----------------

__global__ void k_split_x(const float* __restrict__ x, u16* __restrict__ xh,
                          u16* __restrict__ xl, long n4) {
  const long i = (long)blockIdx.x * blockDim.x + threadIdx.x;
  if (i >= n4) return;
  const float4 v = ((const float4*)x)[i];
  s16x4 h, lo;
  u16 a, b;
  split2(v.x, a, b); h[0] = (short)a; lo[0] = (short)b;
  split2(v.y, a, b); h[1] = (short)a; lo[1] = (short)b;
  split2(v.z, a, b); h[2] = (short)a; lo[2] = (short)b;
  split2(v.w, a, b); h[3] = (short)a; lo[3] = (short)b;
  *(s16x4*)(xh + i * 4) = h;
  *(s16x4*)(xl + i * 4) = lo;
}

// Pack B matrix B[k][j] = src[k*sk + j*sj] into MFMA-fragment order:
// frag (kt,jt), lane l holds B[kt*32 + (l>>4)*8 + i][jt*16 + (l&15)], i=0..7.
__global__ void k_pack_b(const float* __restrict__ src, long sk, long sj, int jtiles,
                         int total, u16* __restrict__ dh, u16* __restrict__ dl) {
  const int fid = blockIdx.x * blockDim.x + threadIdx.x;
  if (fid >= total) return;
  const int lane = fid & 63;
  const int tt = fid >> 6;
  const int jt = tt % jtiles;
  const int kt = tt / jtiles;
  const int k0 = kt * 32 + (lane >> 4) * 8;
  const long j = jt * 16 + (lane & 15);
  s16x8 hv, lv;
#pragma unroll
  for (int i = 0; i < 8; ++i) {
    const float v = src[(long)(k0 + i) * sk + j * sj];
    u16 hh, ll; split2(v, hh, ll);
    hv[i] = (short)hh; lv[i] = (short)ll;
  }
  *(s16x8*)(dh + (long)fid * 8) = hv;
  *(s16x8*)(dl + (long)fid * 8) = lv;
}

// Split to row-major hi/lo: dst[k*nj + j] = split(src[k*sk + j*sj]).
__global__ void k_split_strided(const float* __restrict__ src, long sk, long sj, int nj,
                                long total, u16* __restrict__ dh, u16* __restrict__ dl) {
  const long i = (long)blockIdx.x * blockDim.x + threadIdx.x;
  if (i >= total) return;
  const long k = i / nj;
  const long j = i % nj;
  u16 hh, ll;
  split2(src[k * sk + j * sj], hh, ll);
  dh[i] = hh;
  dl[i] = ll;
}

// ---------------- generic bf16x3 GEMM (A rm-split, B pack-split) ----------------
// C[m,n] = sum_k A[m,k]*B[k,n] (+ bias[n] if ADDB). Block 128x128, 4 waves 2x2.
template <int ADDB>
__global__ __launch_bounds__(256) void k_gemm3(
    const u16* __restrict__ ahi, const u16* __restrict__ alo, long lda,
    const u16* __restrict__ bhi, const u16* __restrict__ blo, int ksteps,
    const float* __restrict__ bias, float* __restrict__ cout, long ldc) {
  const int tid = threadIdx.x;
  const int l = tid & 63;
  const int w = tid >> 6;
  const int wr = w >> 1, wc = w & 1;
  const long m0 = (long)blockIdx.x * 128 + wr * 64;
  const int n0 = blockIdx.y * 128 + wc * 64;
  const int arow = l & 15, koff = (l >> 4) * 8;
  f32x4 acc[4][4];
#pragma unroll
  for (int a = 0; a < 4; ++a)
#pragma unroll
    for (int b = 0; b < 4; ++b) acc[a][b] = (f32x4){0.f, 0.f, 0.f, 0.f};
#pragma unroll 1
  for (int ks = 0; ks < ksteps; ++ks) {
    s16x8 AH[4], AL[4], BH[4], BL[4];
#pragma unroll
    for (int rt = 0; rt < 4; ++rt) {
      const long off = (m0 + rt * 16 + arow) * lda + ks * 32 + koff;
      AH[rt] = *(const s16x8*)(ahi + off);
      AL[rt] = *(const s16x8*)(alo + off);
    }
#pragma unroll
    for (int ct = 0; ct < 4; ++ct) {
      const long off = (((long)ks * NJT + (n0 >> 4) + ct) * 64 + l) * 8;
      BH[ct] = *(const s16x8*)(bhi + off);
      BL[ct] = *(const s16x8*)(blo + off);
    }
#pragma unroll
    for (int ct = 0; ct < 4; ++ct)
#pragma unroll
      for (int rt = 0; rt < 4; ++rt) {
        acc[rt][ct] = MFMA16(AH[rt], BH[ct], acc[rt][ct]);
        acc[rt][ct] = MFMA16(AL[rt], BH[ct], acc[rt][ct]);
        acc[rt][ct] = MFMA16(AH[rt], BL[ct], acc[rt][ct]);
      }
  }
  const int crow = (l >> 4) * 4, ccol = l & 15;
#pragma unroll
  for (int rt = 0; rt < 4; ++rt)
#pragma unroll
    for (int ct = 0; ct < 4; ++ct) {
      const int col = n0 + ct * 16 + ccol;
      const float badd = (ADDB == 1) ? bias[col] : 0.f;
#pragma unroll
      for (int r = 0; r < 4; ++r) {
        const long row = m0 + rt * 16 + crow + r;
        cout[row * ldc + col] = acc[rt][ct][r] + badd;
      }
    }
}

// ---------------- software grid barrier ----------------
__device__ __forceinline__ void gbar(u32* cnt, u32* gen, u32 nb) {
  __syncthreads();
  if (threadIdx.x == 0) {
    __threadfence();
    const u32 g = atomicAdd(gen, 0u);
    if (atomicAdd(cnt, 1u) == nb - 1u) {
      atomicExch(cnt, 0u);
      __threadfence();
      atomicAdd(gen, 1u);
    } else {
      while (atomicAdd(gen, 0u) == g) __builtin_amdgcn_s_sleep(16);
    }
    __threadfence();
  }
  __syncthreads();
}

// ---------------- phase C: boundary scan ----------------
// 256 blocks (128 tiles x 2 paths). Path0: S_c = S_{c-1}*WL^T + e_c (write split
// ping-pong). Path1: Z_c = S_{c-1}*W^T + proj[:,c*L-1] (chunk-init for phase D).
__global__ __launch_bounds__(256) void k_boundary(
    u16* sh0, u16* sl0, u16* sh1, u16* sl1,
    const u16* __restrict__ wlh, const u16* __restrict__ wll,
    const u16* __restrict__ wth, const u16* __restrict__ wtl,
    const float* __restrict__ e, const float* __restrict__ proj,
    float* __restrict__ z, u32* cnt, u32* gen) {
  const int path = blockIdx.x >> 7;
  const int tile = blockIdx.x & 127;
  const int tm = tile >> 5, tn = tile & 31;
  const int tid = threadIdx.x;
  const int l = tid & 63;
  const int w = tid >> 6;
  const int wr = w >> 1, wc = w & 1;
  const int row0 = tm * 32 + wr * 16;
  const int col0 = tn * 32 + wc * 16;
  const int jt = col0 >> 4;
  const u16* bh = path ? wth : wlh;
  const u16* bl = path ? wtl : wll;
#pragma unroll 1
  for (int c = 1; c < CCH; ++c) {
    const u16* ah = (c & 1) ? sh0 : sh1;
    const u16* al = (c & 1) ? sl0 : sl1;
    u16* dh = (c & 1) ? sh1 : sh0;
    u16* dl = (c & 1) ? sl1 : sl0;
    f32x4 acc = (f32x4){0.f, 0.f, 0.f, 0.f};
#pragma unroll 4
    for (int ks = 0; ks < 32; ++ks) {
      const long aoff = (long)(row0 + (l & 15)) * HD + ks * 32 + (l >> 4) * 8;
      const s16x8 A = *(const s16x8*)(ah + aoff);
      const s16x8 A2 = *(const s16x8*)(al + aoff);
      const long boff = (((long)ks * NJT + jt) * 64 + l) * 8;
      const s16x8 B = *(const s16x8*)(bh + boff);
      const s16x8 B2 = *(const s16x8*)(bl + boff);
      acc = MFMA16(A, B, acc);
      acc = MFMA16(A2, B, acc);
      acc = MFMA16(A, B2, acc);
    }
    const int crow = (l >> 4) * 4, ccol = l & 15;
    const int col = col0 + ccol;
#pragma unroll
    for (int r = 0; r < 4; ++r) {
      const int row = row0 + crow + r;
      float v = acc[r];
      if (path == 0) {
        v += e[((long)c * NB + row) * HD + col];
        u16 hh, ll; split2(v, hh, ll);
        dh[(long)row * HD + col] = hh;
        dl[(long)row * HD + col] = ll;
      } else {
        v += proj[((long)row * TS + (long)c * LCH - 1) * HD + col];
        z[((long)c * NB + row) * HD + col] = v;
      }
    }
    gbar(cnt, gen, 256u);
  }
}

// ---------------- phases B / D: per-chunk scan ----------------
// 256 blocks = 64 chunks x 4 row-groups of 32. State fp32 in swizzled LDS.
// EMIT=0: local scan from zero-ish init, writes chunk-end e_c.
// EMIT=1: true scan from Z_c (or initial+proj[0]), writes both output copies.
template <int EMIT>
__global__ __launch_bounds__(512, 2) void k_scan(
    const float* proj, const float* __restrict__ initial,
    const u16* __restrict__ wph, const u16* __restrict__ wpl,
    const float* __restrict__ zbuf, float* __restrict__ ebuf,
    float* out1, float* out2) {
  __shared__ float st[32 * HD];
  const int b = blockIdx.x;
  const int c = b >> 2;
  const int g = b & 3;
  const int tid = threadIdx.x;
  const int l = tid & 63;
  const int w = tid >> 6;
  const long t0 = (long)c * LCH;
  const int ccol = l & 15;
  const int q = l >> 4;
  const int jt0 = w * 8;

  // Prefetch proj[t0] into acc-layout regs (used as step-1 accumulator init).
  float pn[2][8][4];
#pragma unroll
  for (int rt = 0; rt < 2; ++rt)
#pragma unroll
    for (int ct = 0; ct < 8; ++ct) {
      const int col = (jt0 + ct) * 16 + ccol;
#pragma unroll
      for (int r = 0; r < 4; ++r) {
        const int n = g * 32 + rt * 16 + q * 4 + r;
        pn[rt][ct][r] = proj[((long)n * TS + t0) * HD + col];
      }
    }
  __syncthreads();  // pn reads complete before any out2 (== proj) writes below

  // Init state (+ for EMIT, write out[t0]).
  for (int i = tid; i < 32 * HD; i += 512) {
    const int r = i >> 10;
    const int col = i & (HD - 1);
    const int n = g * 32 + r;
    float v;
    if (c == 0) {
      v = initial[(long)n * HD + col] + proj[((long)n * TS) * HD + col];
    } else {
      if constexpr (EMIT) v = zbuf[((long)c * NB + n) * HD + col];
      else                v = proj[((long)n * TS + t0 - 1) * HD + col];
    }
    st[swz(r, col)] = v;
    if constexpr (EMIT) {
      const long o = ((long)n * TS + t0) * HD + col;
      out1[o] = v;
      out2[o] = v;
    }
  }
  __syncthreads();

  f32x4 acc[2][8];
#pragma unroll 1
  for (int step = 1; step < LCH; ++step) {
    const long t = t0 + step;
#pragma unroll
    for (int rt = 0; rt < 2; ++rt)
#pragma unroll
      for (int ct = 0; ct < 8; ++ct) {
        acc[rt][ct][0] = pn[rt][ct][0];
        acc[rt][ct][1] = pn[rt][ct][1];
        acc[rt][ct][2] = pn[rt][ct][2];
        acc[rt][ct][3] = pn[rt][ct][3];
      }
#pragma unroll 2
    for (int ks = 0; ks < 32; ++ks) {
      s16x8 ah[2], al[2];
#pragma unroll
      for (int rt = 0; rt < 2; ++rt) {
        const int row = rt * 16 + ccol;  // A-operand row = lane&15
        const int k0 = ks * 32 + q * 8;
        const int key = row & 7;
        const int pg0 = k0 >> 2;
        const f32x4 f0 = *(const f32x4*)&st[row * HD + (((pg0) ^ key) << 2)];
        const f32x4 f1 = *(const f32x4*)&st[row * HD + (((pg0 + 1) ^ key) << 2)];
        float fv[8];
        fv[0] = f0[0]; fv[1] = f0[1]; fv[2] = f0[2]; fv[3] = f0[3];
        fv[4] = f1[0]; fv[5] = f1[1]; fv[6] = f1[2]; fv[7] = f1[3];
        s16x8 hv, lv;
#pragma unroll
        for (int i2 = 0; i2 < 8; ++i2) {
          u16 hh, ll; split2(fv[i2], hh, ll);
          hv[i2] = (short)hh; lv[i2] = (short)ll;
        }
        ah[rt] = hv;
        al[rt] = lv;
      }
#pragma unroll
      for (int ct = 0; ct < 8; ++ct) {
        const long boff = (((long)ks * NJT + jt0 + ct) * 64 + l) * 8;
        const s16x8 bh = *(const s16x8*)(wph + boff);
        const s16x8 bl = *(const s16x8*)(wpl + boff);
#pragma unroll
        for (int rt = 0; rt < 2; ++rt) {
          acc[rt][ct] = MFMA16(ah[rt], bh, acc[rt][ct]);
          acc[rt][ct] = MFMA16(al[rt], bh, acc[rt][ct]);
          acc[rt][ct] = MFMA16(ah[rt], bl, acc[rt][ct]);
        }
      }
    }
    // Prefetch proj[t] for next step (must precede the out2[t] clobber below;
    // ordered by the barrier).
#pragma unroll
    for (int rt = 0; rt < 2; ++rt)
#pragma unroll
      for (int ct = 0; ct < 8; ++ct) {
        const int col = (jt0 + ct) * 16 + ccol;
#pragma unroll
        for (int r = 0; r < 4; ++r) {
          const int n = g * 32 + rt * 16 + q * 4 + r;
          pn[rt][ct][r] = proj[((long)n * TS + t) * HD + col];
        }
      }
    __syncthreads();
#pragma unroll
    for (int rt = 0; rt < 2; ++rt)
#pragma unroll
      for (int ct = 0; ct < 8; ++ct) {
        const int col = (jt0 + ct) * 16 + ccol;
#pragma unroll
        for (int r = 0; r < 4; ++r) {
          const int row = rt * 16 + q * 4 + r;
          const float v = acc[rt][ct][r];
          st[swz(row, col)] = v;
          if constexpr (EMIT) {
            const long o = ((long)(g * 32 + row) * TS + t) * HD + col;
            out1[o] = v;
            out2[o] = v;
          }
        }
      }
    __syncthreads();
  }
  if constexpr (!EMIT) {
    for (int i = tid; i < 32 * HD; i += 512) {
      const int r = i >> 10;
      const int col = i & (HD - 1);
      ebuf[((long)c * NB + g * 32 + r) * HD + col] = st[swz(r, col)];
    }
  }
}

// ---------------- host ----------------

extern "C" void kernel_launch(void* const* d_in, const int* in_sizes, int n_in,
                              void* d_out, int out_size, void* d_ws, size_t ws_size,
                              hipStream_t stream) {
  const float* x = (const float*)d_in[0];
  const float* w_ih = (const float*)d_in[1];
  const float* b_ih = (const float*)d_in[2];
  const float* w_hh = (const float*)d_in[3];
  const float* initial = (const float*)d_in[4];

  char* r1 = (char*)d_out;  // out copy 1: scratch until phase D
  float* out1 = (float*)d_out;
  float* proj = out1 + (long)NB * TS * HD;  // out copy 2: proj scratch
  float* out2 = proj;

  u16* xh = (u16*)(r1 + 0L);
  u16* xl = (u16*)(r1 + 67108864L);
  float* e = (float*)(r1 + 134217728L);
  u16* wt_rm_h = (u16*)(r1 + 167772160L);
  u16* wt_rm_l = (u16*)(r1 + 169869312L);
  float* tmpf = (float*)(r1 + 171966464L);
  u16* prm_h[2] = {(u16*)(r1 + 176160768L), (u16*)(r1 + 178257920L)};
  u16* prm_l[2] = {(u16*)(r1 + 180355072L), (u16*)(r1 + 182452224L)};
  u16* ppk_h[2] = {(u16*)(r1 + 184549376L), (u16*)(r1 + 186646528L)};
  u16* ppk_l[2] = {(u16*)(r1 + 188743680L), (u16*)(r1 + 190840832L)};
  u16* wih_h = (u16*)(r1 + 192937984L);
  u16* wih_l = (u16*)(r1 + 193200128L);
  u16* sp_h[2] = {(u16*)(r1 + 193462272L), (u16*)(r1 + 193724416L)};
  u16* sp_l[2] = {(u16*)(r1 + 193986560L), (u16*)(r1 + 194248704L)};

  char* wsb = (char*)d_ws;
  u16* wt_pk_h = (u16*)(wsb + 0L);
  u16* wt_pk_l = (u16*)(wsb + 2097152L);
  float* zbuf = (float*)(wsb + 4194304L);
  u32* cnt = (u32*)(wsb + 37748736L);
  u32* gen = cnt + 1;

  hipMemsetAsync(cnt, 0, 8, stream);

  // prep: split x, pack W^T matrices
  k_split_x<<<32768, 256, 0, stream>>>(x, xh, xl, (long)NB * TS * ID / 4);
  // Wt[k][j] = w_hh[j][k]  (sk=1, sj=HD)
  k_pack_b<<<512, 256, 0, stream>>>(w_hh, 1L, (long)HD, NJT, 32 * NJT * 64, wt_pk_h, wt_pk_l);
  // wihT[i][h] = w_ih[h][i]  (sk=1, sj=ID)
  k_pack_b<<<64, 256, 0, stream>>>(w_ih, 1L, (long)ID, NJT, 4 * NJT * 64, wih_h, wih_l);
  k_split_strided<<<4096, 256, 0, stream>>>(w_hh, 1L, (long)HD, HD, (long)HD * HD, wt_rm_h, wt_rm_l);

  // phase A: proj = x @ w_ih^T + b_ih
  dim3 gproj(2048, 8);
  k_gemm3<1><<<gproj, 256, 0, stream>>>(xh, xl, (long)ID, wih_h, wih_l, ID / 32, b_ih, proj, (long)HD);

  // W^L squaring chain (L=32 -> 5 squarings), all in transposed space
  const u16 *arh = wt_rm_h, *arl = wt_rm_l, *aph = wt_pk_h, *apl = wt_pk_l;
  dim3 g88(8, 8);
  for (int i = 0; i < 5; ++i) {
    const int s = i & 1;
    k_gemm3<0><<<g88, 256, 0, stream>>>(arh, arl, (long)HD, aph, apl, HD / 32, nullptr, tmpf, (long)HD);
    k_split_strided<<<4096, 256, 0, stream>>>(tmpf, (long)HD, 1L, HD, (long)HD * HD, prm_h[s], prm_l[s]);
    k_pack_b<<<512, 256, 0, stream>>>(tmpf, (long)HD, 1L, NJT, 32 * NJT * 64, ppk_h[s], ppk_l[s]);
    arh = prm_h[s]; arl = prm_l[s]; aph = ppk_h[s]; apl = ppk_l[s];
  }

  // phase B: per-chunk local scans -> e_c
  k_scan<0><<<256, 512, 0, stream>>>(proj, initial, wt_pk_h, wt_pk_l, nullptr, e, nullptr, nullptr);

  // split e_0 -> S ping-pong slot 0
  k_split_strided<<<512, 256, 0, stream>>>(e, (long)HD, 1L, HD, (long)NB * HD, sp_h[0], sp_l[0]);

  // phase C: boundary scan (S_c and Z_c), software grid barrier
  k_boundary<<<256, 256, 0, stream>>>(sp_h[0], sp_l[0], sp_h[1], sp_l[1], aph, apl,
                                      wt_pk_h, wt_pk_l, e, proj, zbuf, cnt, gen);

  // phase D: emit all hidden states (both output copies)
  k_scan<1><<<256, 512, 0, stream>>>(proj, initial, wt_pk_h, wt_pk_l, zbuf, nullptr, out1, out2);
}

// Round 2
// 9300.436 us; speedup vs baseline: 1.0523x; 1.0523x over previous
//
// Chunked parallel linear-RNN scan for MI355X (gfx950), bf16x3 split MFMA.
//   proj = x @ w_ih^T + b_ih                      (gemm3, K=128)
//   h_t  = h_{t-1} @ w_hh^T + proj[t-1]           (chunked scan)
// R2: k_scan state kept as bf16 hi/lo planes in LDS (split once by producer,
// direct ds_read_b128 A-fragments), NT loads/stores for streaming data so the
// 4MB W-pack stays L2-resident, proj prefetch hoisted above the MFMA loop,
// squaring-chain GEMM retiled to 64x64 (256 blocks).

#include <hip/hip_runtime.h>
#include <stdint.h>

typedef unsigned int u32;
typedef unsigned short u16;
typedef __attribute__((ext_vector_type(4))) float f32x4;
typedef __attribute__((ext_vector_type(8))) short s16x8;
typedef __attribute__((ext_vector_type(4))) short s16x4;

#define NB 128
#define TS 2048
#define ID 128
#define HD 1024
#define LCH 32
#define CCH 64
#define NJT 64  // HD/16

__device__ __forceinline__ u16 f2bf(float f) {
  u32 u = __builtin_bit_cast(u32, f);
  u += 0x7FFFu + ((u >> 16) & 1u);
  return (u16)(u >> 16);
}
__device__ __forceinline__ float bf2f(u16 h) {
  u32 u = ((u32)h) << 16;
  return __builtin_bit_cast(float, u);
}
__device__ __forceinline__ void split2(float f, u16& hi, u16& lo) {
  hi = f2bf(f);
  lo = f2bf(f - bf2f(hi));
}
__device__ __forceinline__ float ntl(const float* p) { return __builtin_nontemporal_load(p); }
__device__ __forceinline__ void nts(float v, float* p) { __builtin_nontemporal_store(v, p); }
#define MFMA16(a, b, c) __builtin_amdgcn_mfma_f32_16x16x32_bf16((a), (b), (c), 0, 0, 0)

// ---------------- prep kernels ----------------

__global__ void k_split_x(const float* __restrict__ x, u16* __restrict__ xh,
                          u16* __restrict__ xl, long n4) {
  const long i = (long)blockIdx.x * blockDim.x + threadIdx.x;
  if (i >= n4) return;
  const float4 v = ((const float4*)x)[i];
  s16x4 h, lo;
  u16 a, b;
  split2(v.x, a, b); h[0] = (short)a; lo[0] = (short)b;
  split2(v.y, a, b); h[1] = (short)a; lo[1] = (short)b;
  split2(v.z, a, b); h[2] = (short)a; lo[2] = (short)b;
  split2(v.w, a, b); h[3] = (short)a; lo[3] = (short)b;
  *(s16x4*)(xh + i * 4) = h;
  *(s16x4*)(xl + i * 4) = lo;
}

// Pack B matrix B[k][j] = src[k*sk + j*sj] into MFMA-fragment order:
// frag (kt,jt), lane l holds B[kt*32 + (l>>4)*8 + i][jt*16 + (l&15)], i=0..7.
__global__ void k_pack_b(const float* __restrict__ src, long sk, long sj, int jtiles,
                         int total, u16* __restrict__ dh, u16* __restrict__ dl) {
  const int fid = blockIdx.x * blockDim.x + threadIdx.x;
  if (fid >= total) return;
  const int lane = fid & 63;
  const int tt = fid >> 6;
  const int jt = tt % jtiles;
  const int kt = tt / jtiles;
  const int k0 = kt * 32 + (lane >> 4) * 8;
  const long j = jt * 16 + (lane & 15);
  s16x8 hv, lv;
#pragma unroll
  for (int i = 0; i < 8; ++i) {
    const float v = src[(long)(k0 + i) * sk + j * sj];
    u16 hh, ll; split2(v, hh, ll);
    hv[i] = (short)hh; lv[i] = (short)ll;
  }
  *(s16x8*)(dh + (long)fid * 8) = hv;
  *(s16x8*)(dl + (long)fid * 8) = lv;
}

// Split to row-major hi/lo: dst[k*nj + j] = split(src[k*sk + j*sj]).
__global__ void k_split_strided(const float* __restrict__ src, long sk, long sj, int nj,
                                long total, u16* __restrict__ dh, u16* __restrict__ dl) {
  const long i = (long)blockIdx.x * blockDim.x + threadIdx.x;
  if (i >= total) return;
  const long k = i / nj;
  const long j = i % nj;
  u16 hh, ll;
  split2(src[k * sk + j * sj], hh, ll);
  dh[i] = hh;
  dl[i] = ll;
}

// ---------------- generic bf16x3 GEMM (A rm-split, B pack-split) ----------------
// C[m,n] = sum_k A[m,k]*B[k,n] (+ bias[n] if ADDB). Block (32*RT)x(32*CT),
// 4 waves 2x2, wave tile (16*RT)x(16*CT). NT store for C.
template <int ADDB, int RT, int CT>
__global__ __launch_bounds__(256) void k_gemm3(
    const u16* __restrict__ ahi, const u16* __restrict__ alo, long lda,
    const u16* __restrict__ bhi, const u16* __restrict__ blo, int ksteps,
    const float* __restrict__ bias, float* __restrict__ cout, long ldc) {
  const int tid = threadIdx.x;
  const int l = tid & 63;
  const int w = tid >> 6;
  const int wr = w >> 1, wc = w & 1;
  const long m0 = (long)blockIdx.x * (32 * RT) + wr * (16 * RT);
  const int n0 = blockIdx.y * (32 * CT) + wc * (16 * CT);
  const int arow = l & 15, koff = (l >> 4) * 8;
  f32x4 acc[RT][CT];
#pragma unroll
  for (int a = 0; a < RT; ++a)
#pragma unroll
    for (int b = 0; b < CT; ++b) acc[a][b] = (f32x4){0.f, 0.f, 0.f, 0.f};
#pragma unroll 1
  for (int ks = 0; ks < ksteps; ++ks) {
    s16x8 AH[RT], AL[RT], BH[CT], BL[CT];
#pragma unroll
    for (int rt = 0; rt < RT; ++rt) {
      const long off = (m0 + rt * 16 + arow) * lda + ks * 32 + koff;
      AH[rt] = *(const s16x8*)(ahi + off);
      AL[rt] = *(const s16x8*)(alo + off);
    }
#pragma unroll
    for (int ct = 0; ct < CT; ++ct) {
      const long off = (((long)ks * NJT + (n0 >> 4) + ct) * 64 + l) * 8;
      BH[ct] = *(const s16x8*)(bhi + off);
      BL[ct] = *(const s16x8*)(blo + off);
    }
#pragma unroll
    for (int ct = 0; ct < CT; ++ct)
#pragma unroll
      for (int rt = 0; rt < RT; ++rt) {
        acc[rt][ct] = MFMA16(AH[rt], BH[ct], acc[rt][ct]);
        acc[rt][ct] = MFMA16(AL[rt], BH[ct], acc[rt][ct]);
        acc[rt][ct] = MFMA16(AH[rt], BL[ct], acc[rt][ct]);
      }
  }
  const int crow = (l >> 4) * 4, ccol = l & 15;
#pragma unroll
  for (int rt = 0; rt < RT; ++rt)
#pragma unroll
    for (int ct = 0; ct < CT; ++ct) {
      const int col = n0 + ct * 16 + ccol;
      const float badd = (ADDB == 1) ? bias[col] : 0.f;
#pragma unroll
      for (int r = 0; r < 4; ++r) {
        const long row = m0 + rt * 16 + crow + r;
        nts(acc[rt][ct][r] + badd, cout + row * ldc + col);
      }
    }
}

// ---------------- software grid barrier ----------------
__device__ __forceinline__ void gbar(u32* cnt, u32* gen, u32 nb) {
  __syncthreads();
  if (threadIdx.x == 0) {
    __threadfence();
    const u32 g = atomicAdd(gen, 0u);
    if (atomicAdd(cnt, 1u) == nb - 1u) {
      atomicExch(cnt, 0u);
      __threadfence();
      atomicAdd(gen, 1u);
    } else {
      while (atomicAdd(gen, 0u) == g) __builtin_amdgcn_s_sleep(16);
    }
    __threadfence();
  }
  __syncthreads();
}

// ---------------- phase C: boundary scan ----------------
// 256 blocks (128 tiles x 2 paths). Path0: S_c = S_{c-1}*WL^T + e_c (write split
// ping-pong). Path1: Z_c = S_{c-1}*W^T + proj[:,c*L-1] (chunk-init for phase D).
__global__ __launch_bounds__(256) void k_boundary(
    u16* sh0, u16* sl0, u16* sh1, u16* sl1,
    const u16* __restrict__ wlh, const u16* __restrict__ wll,
    const u16* __restrict__ wth, const u16* __restrict__ wtl,
    const float* __restrict__ e, const float* __restrict__ proj,
    float* __restrict__ z, u32* cnt, u32* gen) {
  const int path = blockIdx.x >> 7;
  const int tile = blockIdx.x & 127;
  const int tm = tile >> 5, tn = tile & 31;
  const int tid = threadIdx.x;
  const int l = tid & 63;
  const int w = tid >> 6;
  const int wr = w >> 1, wc = w & 1;
  const int row0 = tm * 32 + wr * 16;
  const int col0 = tn * 32 + wc * 16;
  const int jt = col0 >> 4;
  const u16* bh = path ? wth : wlh;
  const u16* bl = path ? wtl : wll;
#pragma unroll 1
  for (int c = 1; c < CCH; ++c) {
    const u16* ah = (c & 1) ? sh0 : sh1;
    const u16* al = (c & 1) ? sl0 : sl1;
    u16* dh = (c & 1) ? sh1 : sh0;
    u16* dl = (c & 1) ? sl1 : sl0;
    f32x4 acc = (f32x4){0.f, 0.f, 0.f, 0.f};
#pragma unroll 4
    for (int ks = 0; ks < 32; ++ks) {
      const long aoff = (long)(row0 + (l & 15)) * HD + ks * 32 + (l >> 4) * 8;
      const s16x8 A = *(const s16x8*)(ah + aoff);
      const s16x8 A2 = *(const s16x8*)(al + aoff);
      const long boff = (((long)ks * NJT + jt) * 64 + l) * 8;
      const s16x8 B = *(const s16x8*)(bh + boff);
      const s16x8 B2 = *(const s16x8*)(bl + boff);
      acc = MFMA16(A, B, acc);
      acc = MFMA16(A2, B, acc);
      acc = MFMA16(A, B2, acc);
    }
    const int crow = (l >> 4) * 4, ccol = l & 15;
    const int col = col0 + ccol;
#pragma unroll
    for (int r = 0; r < 4; ++r) {
      const int row = row0 + crow + r;
      float v = acc[r];
      if (path == 0) {
        v += e[((long)c * NB + row) * HD + col];
        u16 hh, ll; split2(v, hh, ll);
        dh[(long)row * HD + col] = hh;
        dl[(long)row * HD + col] = ll;
      } else {
        v += proj[((long)row * TS + (long)c * LCH - 1) * HD + col];
        z[((long)c * NB + row) * HD + col] = v;
      }
    }
    gbar(cnt, gen, 256u);
  }
}

// ---------------- phases B / D: per-chunk scan ----------------
// 256 blocks = 64 chunks x 4 row-groups of 32. State as bf16 hi/lo planes in
// LDS (XOR-swizzled 16B blocks), split once by producer threads.
// EMIT=0: local scan, writes chunk-end e_c.  EMIT=1: true scan from Z_c,
// writes both output copies (NT).
template <int EMIT>
__global__ __launch_bounds__(512, 2) void k_scan(
    const float* proj, const float* __restrict__ initial,
    const u16* __restrict__ wph, const u16* __restrict__ wpl,
    const float* __restrict__ zbuf, float* __restrict__ ebuf,
    float* out1, float* out2) {
  __shared__ u16 sh[32 * HD];
  __shared__ u16 sl[32 * HD];
  const int b = blockIdx.x;
  const int c = b >> 2;
  const int g = b & 3;
  const int tid = threadIdx.x;
  const int l = tid & 63;
  const int w = tid >> 6;
  const long t0 = (long)c * LCH;
  const int ccol = l & 15;
  const int q = l >> 4;
  const int jt0 = w * 8;
  const int akey = l & 7;            // (row&7) for A-fragment reads (rt*16 preserves low 3 bits)
  const int rowoff0 = ccol * HD;     // rt=0 row base
  const int rowoff1 = (16 + ccol) * HD;

  // Prefetch proj[t0] into acc-layout regs (step-1 accumulator init).
  float pn[2][8][4];
#pragma unroll
  for (int rt = 0; rt < 2; ++rt)
#pragma unroll
    for (int ct = 0; ct < 8; ++ct) {
      const int col = (jt0 + ct) * 16 + ccol;
#pragma unroll
      for (int r = 0; r < 4; ++r) {
        const int n = g * 32 + rt * 16 + q * 4 + r;
        pn[rt][ct][r] = ntl(proj + ((long)n * TS + t0) * HD + col);
      }
    }
  __syncthreads();  // pn loads drained before any out2 (== proj) writes below

  // Init state planes (+ for EMIT, write out[t0]).
  for (int i = tid; i < 32 * HD; i += 512) {
    const int r = i >> 10;
    const int col = i & (HD - 1);
    const int n = g * 32 + r;
    float v;
    if (c == 0) {
      v = ntl(initial + (long)n * HD + col) + ntl(proj + ((long)n * TS) * HD + col);
    } else {
      if constexpr (EMIT) v = ntl(zbuf + ((long)c * NB + n) * HD + col);
      else                v = ntl(proj + ((long)n * TS + t0 - 1) * HD + col);
    }
    u16 hh, ll; split2(v, hh, ll);
    const int si = r * HD + ((((col >> 3) ^ (r & 7)) << 3) | (col & 7));
    sh[si] = hh; sl[si] = ll;
    if constexpr (EMIT) {
      const long o = ((long)n * TS + t0) * HD + col;
      nts(v, out1 + o); nts(v, out2 + o);
    }
  }
  __syncthreads();

  f32x4 acc[2][8];
#pragma unroll 1
  for (int step = 1; step < LCH; ++step) {
    const long t = t0 + step;
    // acc <- pn (proj[t-1])
#pragma unroll
    for (int rt = 0; rt < 2; ++rt)
#pragma unroll
      for (int ct = 0; ct < 8; ++ct) {
        acc[rt][ct][0] = pn[rt][ct][0];
        acc[rt][ct][1] = pn[rt][ct][1];
        acc[rt][ct][2] = pn[rt][ct][2];
        acc[rt][ct][3] = pn[rt][ct][3];
      }
    // Prefetch proj[t] for next step; latency hides under the MFMA loop.
    // (Safe vs the EMIT out2[t] alias: the pre-write barrier drains vmcnt.)
#pragma unroll
    for (int rt = 0; rt < 2; ++rt)
#pragma unroll
      for (int ct = 0; ct < 8; ++ct) {
        const int col = (jt0 + ct) * 16 + ccol;
#pragma unroll
        for (int r = 0; r < 4; ++r) {
          const int n = g * 32 + rt * 16 + q * 4 + r;
          pn[rt][ct][r] = ntl(proj + ((long)n * TS + t) * HD + col);
        }
      }
#pragma unroll 2
    for (int ks = 0; ks < 32; ++ks) {
      const int colpart = ((((ks << 2) | q) ^ akey) << 3);
      const s16x8 ah0 = *(const s16x8*)&sh[rowoff0 + colpart];
      const s16x8 al0 = *(const s16x8*)&sl[rowoff0 + colpart];
      const s16x8 ah1 = *(const s16x8*)&sh[rowoff1 + colpart];
      const s16x8 al1 = *(const s16x8*)&sl[rowoff1 + colpart];
#pragma unroll
      for (int ct = 0; ct < 8; ++ct) {
        const long boff = (((long)ks * NJT + jt0 + ct) * 64 + l) * 8;
        const s16x8 bh = *(const s16x8*)(wph + boff);
        const s16x8 bl = *(const s16x8*)(wpl + boff);
        acc[0][ct] = MFMA16(ah0, bh, acc[0][ct]);
        acc[0][ct] = MFMA16(al0, bh, acc[0][ct]);
        acc[0][ct] = MFMA16(ah0, bl, acc[0][ct]);
        acc[1][ct] = MFMA16(ah1, bh, acc[1][ct]);
        acc[1][ct] = MFMA16(al1, bh, acc[1][ct]);
        acc[1][ct] = MFMA16(ah1, bl, acc[1][ct]);
      }
    }
    __syncthreads();  // all plane reads done; also drains the pn prefetch
    // Producer write-back: split once, store planes (+ NT emit).
#pragma unroll
    for (int rt = 0; rt < 2; ++rt)
#pragma unroll
      for (int ct = 0; ct < 8; ++ct) {
        const int colb = (jt0 + ct) * 16 + ccol;
        const int cb7 = colb & 7;
        const int cblk = colb >> 3;
#pragma unroll
        for (int r = 0; r < 4; ++r) {
          const int row = rt * 16 + q * 4 + r;
          const float v = acc[rt][ct][r];
          u16 hh, ll; split2(v, hh, ll);
          const int si = row * HD + (((cblk ^ (row & 7)) << 3) | cb7);
          sh[si] = hh; sl[si] = ll;
          if constexpr (EMIT) {
            const long o = ((long)(g * 32 + row) * TS + t) * HD + colb;
            nts(v, out1 + o); nts(v, out2 + o);
          }
        }
      }
    __syncthreads();
  }
  if constexpr (!EMIT) {
    for (int i = tid; i < 32 * HD; i += 512) {
      const int r = i >> 10;
      const int col = i & (HD - 1);
      const int si = r * HD + ((((col >> 3) ^ (r & 7)) << 3) | (col & 7));
      const float v = bf2f(sh[si]) + bf2f(sl[si]);
      ebuf[((long)c * NB + g * 32 + r) * HD + col] = v;
    }
  }
}

// ---------------- host ----------------

extern "C" void kernel_launch(void* const* d_in, const int* in_sizes, int n_in,
                              void* d_out, int out_size, void* d_ws, size_t ws_size,
                              hipStream_t stream) {
  const float* x = (const float*)d_in[0];
  const float* w_ih = (const float*)d_in[1];
  const float* b_ih = (const float*)d_in[2];
  const float* w_hh = (const float*)d_in[3];
  const float* initial = (const float*)d_in[4];

  char* r1 = (char*)d_out;  // out copy 1: scratch until phase D
  float* out1 = (float*)d_out;
  float* proj = out1 + (long)NB * TS * HD;  // out copy 2: proj scratch
  float* out2 = proj;

  u16* xh = (u16*)(r1 + 0L);
  u16* xl = (u16*)(r1 + 67108864L);
  float* e = (float*)(r1 + 134217728L);
  u16* wt_rm_h = (u16*)(r1 + 167772160L);
  u16* wt_rm_l = (u16*)(r1 + 169869312L);
  float* tmpf = (float*)(r1 + 171966464L);
  u16* prm_h[2] = {(u16*)(r1 + 176160768L), (u16*)(r1 + 178257920L)};
  u16* prm_l[2] = {(u16*)(r1 + 180355072L), (u16*)(r1 + 182452224L)};
  u16* ppk_h[2] = {(u16*)(r1 + 184549376L), (u16*)(r1 + 186646528L)};
  u16* ppk_l[2] = {(u16*)(r1 + 188743680L), (u16*)(r1 + 190840832L)};
  u16* wih_h = (u16*)(r1 + 192937984L);
  u16* wih_l = (u16*)(r1 + 193200128L);
  u16* sp_h[2] = {(u16*)(r1 + 193462272L), (u16*)(r1 + 193724416L)};
  u16* sp_l[2] = {(u16*)(r1 + 193986560L), (u16*)(r1 + 194248704L)};

  char* wsb = (char*)d_ws;
  u16* wt_pk_h = (u16*)(wsb + 0L);
  u16* wt_pk_l = (u16*)(wsb + 2097152L);
  float* zbuf = (float*)(wsb + 4194304L);
  u32* cnt = (u32*)(wsb + 37748736L);
  u32* gen = cnt + 1;

  hipMemsetAsync(cnt, 0, 8, stream);

  // prep: split x, pack W^T matrices
  k_split_x<<<32768, 256, 0, stream>>>(x, xh, xl, (long)NB * TS * ID / 4);
  // Wt[k][j] = w_hh[j][k]  (sk=1, sj=HD)
  k_pack_b<<<512, 256, 0, stream>>>(w_hh, 1L, (long)HD, NJT, 32 * NJT * 64, wt_pk_h, wt_pk_l);
  // wihT[i][h] = w_ih[h][i]  (sk=1, sj=ID)
  k_pack_b<<<64, 256, 0, stream>>>(w_ih, 1L, (long)ID, NJT, 4 * NJT * 64, wih_h, wih_l);
  k_split_strided<<<4096, 256, 0, stream>>>(w_hh, 1L, (long)HD, HD, (long)HD * HD, wt_rm_h, wt_rm_l);

  // phase A: proj = x @ w_ih^T + b_ih
  dim3 gproj(2048, 8);
  k_gemm3<1, 4, 4><<<gproj, 256, 0, stream>>>(xh, xl, (long)ID, wih_h, wih_l, ID / 32, b_ih, proj, (long)HD);

  // W^L squaring chain (L=32 -> 5 squarings), all in transposed space
  const u16 *arh = wt_rm_h, *arl = wt_rm_l, *aph = wt_pk_h, *apl = wt_pk_l;
  dim3 g1616(16, 16);
  for (int i = 0; i < 5; ++i) {
    const int s = i & 1;
    k_gemm3<0, 2, 2><<<g1616, 256, 0, stream>>>(arh, arl, (long)HD, aph, apl, HD / 32, nullptr, tmpf, (long)HD);
    k_split_strided<<<4096, 256, 0, stream>>>(tmpf, (long)HD, 1L, HD, (long)HD * HD, prm_h[s], prm_l[s]);
    k_pack_b<<<512, 256, 0, stream>>>(tmpf, (long)HD, 1L, NJT, 32 * NJT * 64, ppk_h[s], ppk_l[s]);
    arh = prm_h[s]; arl = prm_l[s]; aph = ppk_h[s]; apl = ppk_l[s];
  }

  // phase B: per-chunk local scans -> e_c
  k_scan<0><<<256, 512, 0, stream>>>(proj, initial, wt_pk_h, wt_pk_l, nullptr, e, nullptr, nullptr);

  // split e_0 -> S ping-pong slot 0
  k_split_strided<<<512, 256, 0, stream>>>(e, (long)HD, 1L, HD, (long)NB * HD, sp_h[0], sp_l[0]);

  // phase C: boundary scan (S_c and Z_c), software grid barrier
  k_boundary<<<256, 256, 0, stream>>>(sp_h[0], sp_l[0], sp_h[1], sp_l[1], aph, apl,
                                      wt_pk_h, wt_pk_l, e, proj, zbuf, cnt, gen);

  // phase D: emit all hidden states (both output copies)
  k_scan<1><<<256, 512, 0, stream>>>(proj, initial, wt_pk_h, wt_pk_l, zbuf, nullptr, out1, out2);
}

// Round 3
// 6857.223 us; speedup vs baseline: 1.4272x; 1.3563x over previous
//
// Chunked parallel linear-RNN scan for MI355X (gfx950), bf16x3 split MFMA.
//   proj = x @ w_ih^T + b_ih                      (gemm3, K=128)
//   h_t  = h_{t-1} @ w_hh^T + proj[t-1]           (chunked scan)
// R3: k_scan 16 waves/block (4/SIMD, 2x TLP for L2 latency hiding);
// squaring chain fused (GEMM epilogue writes rm+pack planes directly);
// boundary = serial S-chain only (128 blocks, 62 barriers) + parallel Z GEMM.

#include <hip/hip_runtime.h>
#include <stdint.h>

typedef unsigned int u32;
typedef unsigned short u16;
typedef __attribute__((ext_vector_type(4))) float f32x4;
typedef __attribute__((ext_vector_type(8))) short s16x8;
typedef __attribute__((ext_vector_type(4))) short s16x4;

#define NB 128
#define TS 2048
#define ID 128
#define HD 1024
#define LCH 32
#define CCH 64
#define NJT 64  // HD/16

__device__ __forceinline__ u16 f2bf(float f) {
  u32 u = __builtin_bit_cast(u32, f);
  u += 0x7FFFu + ((u >> 16) & 1u);
  return (u16)(u >> 16);
}
__device__ __forceinline__ float bf2f(u16 h) {
  u32 u = ((u32)h) << 16;
  return __builtin_bit_cast(float, u);
}
__device__ __forceinline__ void split2(float f, u16& hi, u16& lo) {
  hi = f2bf(f);
  lo = f2bf(f - bf2f(hi));
}
__device__ __forceinline__ float ntl(const float* p) { return __builtin_nontemporal_load(p); }
__device__ __forceinline__ void nts(float v, float* p) { __builtin_nontemporal_store(v, p); }
#define MFMA16(a, b, c) __builtin_amdgcn_mfma_f32_16x16x32_bf16((a), (b), (c), 0, 0, 0)

// ---------------- prep kernels ----------------

__global__ void k_split_x(const float* __restrict__ x, u16* __restrict__ xh,
                          u16* __restrict__ xl, long n4) {
  const long i = (long)blockIdx.x * blockDim.x + threadIdx.x;
  if (i >= n4) return;
  const float4 v = ((const float4*)x)[i];
  s16x4 h, lo;
  u16 a, b;
  split2(v.x, a, b); h[0] = (short)a; lo[0] = (short)b;
  split2(v.y, a, b); h[1] = (short)a; lo[1] = (short)b;
  split2(v.z, a, b); h[2] = (short)a; lo[2] = (short)b;
  split2(v.w, a, b); h[3] = (short)a; lo[3] = (short)b;
  *(s16x4*)(xh + i * 4) = h;
  *(s16x4*)(xl + i * 4) = lo;
}

// Pack B[k][j] = src[k*sk + j*sj] into MFMA-fragment order:
// frag (kt,jt), lane l holds B[kt*32 + (l>>4)*8 + i][jt*16 + (l&15)], i=0..7.
__global__ void k_pack_b(const float* __restrict__ src, long sk, long sj, int jtiles,
                         int total, u16* __restrict__ dh, u16* __restrict__ dl) {
  const int fid = blockIdx.x * blockDim.x + threadIdx.x;
  if (fid >= total) return;
  const int lane = fid & 63;
  const int tt = fid >> 6;
  const int jt = tt % jtiles;
  const int kt = tt / jtiles;
  const int k0 = kt * 32 + (lane >> 4) * 8;
  const long j = jt * 16 + (lane & 15);
  s16x8 hv, lv;
#pragma unroll
  for (int i = 0; i < 8; ++i) {
    const float v = src[(long)(k0 + i) * sk + j * sj];
    u16 hh, ll; split2(v, hh, ll);
    hv[i] = (short)hh; lv[i] = (short)ll;
  }
  *(s16x8*)(dh + (long)fid * 8) = hv;
  *(s16x8*)(dl + (long)fid * 8) = lv;
}

// Split to row-major hi/lo planes: dst[k*nj + j] = split(src[k*sk + j*sj]).
__global__ void k_split_strided(const float* __restrict__ src, long sk, long sj, int nj,
                                long total, u16* __restrict__ dh, u16* __restrict__ dl) {
  const long i = (long)blockIdx.x * blockDim.x + threadIdx.x;
  if (i >= total) return;
  const long k = i / nj;
  const long j = i % nj;
  u16 hh, ll;
  split2(src[k * sk + j * sj], hh, ll);
  dh[i] = hh;
  dl[i] = ll;
}

// ---------------- generic bf16x3 GEMM (A rm-split, B pack-split) ----------------
// C[m,n] = sum_k A[m,k]*B[k,n]. Block (32*RT)x(32*CT), 4 waves 2x2.
// EPI 1: +bias(aux), NT store to cout.
// EPI 2: + aux=proj gather (Z-init epilogue), store to cout=zbuf.
// EPI 3: write rm hi/lo planes (drm_h/l) AND packed hi/lo planes (dpk_h/l).
template <int EPI, int RT, int CT>
__global__ __launch_bounds__(256) void k_gemm3(
    const u16* __restrict__ ahi, const u16* __restrict__ alo, long lda,
    const u16* __restrict__ bhi, const u16* __restrict__ blo, int ksteps,
    const float* __restrict__ aux, float* __restrict__ cout, long ldc,
    u16* __restrict__ drm_h, u16* __restrict__ drm_l,
    u16* __restrict__ dpk_h, u16* __restrict__ dpk_l) {
  const int tid = threadIdx.x;
  const int l = tid & 63;
  const int w = tid >> 6;
  const int wr = w >> 1, wc = w & 1;
  const long m0 = (long)blockIdx.x * (32 * RT) + wr * (16 * RT);
  const int n0 = blockIdx.y * (32 * CT) + wc * (16 * CT);
  const int arow = l & 15, koff = (l >> 4) * 8;
  f32x4 acc[RT][CT];
#pragma unroll
  for (int a = 0; a < RT; ++a)
#pragma unroll
    for (int b = 0; b < CT; ++b) acc[a][b] = (f32x4){0.f, 0.f, 0.f, 0.f};
#pragma unroll 1
  for (int ks = 0; ks < ksteps; ++ks) {
    s16x8 AH[RT], AL[RT], BH[CT], BL[CT];
#pragma unroll
    for (int rt = 0; rt < RT; ++rt) {
      const long off = (m0 + rt * 16 + arow) * lda + ks * 32 + koff;
      AH[rt] = *(const s16x8*)(ahi + off);
      AL[rt] = *(const s16x8*)(alo + off);
    }
#pragma unroll
    for (int ct = 0; ct < CT; ++ct) {
      const long off = (((long)ks * NJT + (n0 >> 4) + ct) * 64 + l) * 8;
      BH[ct] = *(const s16x8*)(bhi + off);
      BL[ct] = *(const s16x8*)(blo + off);
    }
#pragma unroll
    for (int ct = 0; ct < CT; ++ct)
#pragma unroll
      for (int rt = 0; rt < RT; ++rt) {
        acc[rt][ct] = MFMA16(AH[rt], BH[ct], acc[rt][ct]);
        acc[rt][ct] = MFMA16(AL[rt], BH[ct], acc[rt][ct]);
        acc[rt][ct] = MFMA16(AH[rt], BL[ct], acc[rt][ct]);
      }
  }
  const int crow = (l >> 4) * 4, ccol = l & 15;
#pragma unroll
  for (int rt = 0; rt < RT; ++rt)
#pragma unroll
    for (int ct = 0; ct < CT; ++ct) {
      const int col = n0 + ct * 16 + ccol;
#pragma unroll
      for (int r = 0; r < 4; ++r) {
        const long row = m0 + rt * 16 + crow + r;
        const float v = acc[rt][ct][r];
        if constexpr (EPI == 1) {
          nts(v + aux[col], cout + row * ldc + col);
        } else if constexpr (EPI == 2) {
          const int c = (int)(row >> 7) + 1;
          const int n = (int)(row & 127);
          const float z = v + aux[((long)n * TS + (long)c * LCH - 1) * HD + col];
          cout[(((long)c * NB) + n) * HD + col] = z;
        } else {
          u16 hh, ll; split2(v, hh, ll);
          drm_h[row * HD + col] = hh;
          drm_l[row * HD + col] = ll;
          const int lane2 = ((((int)row >> 3) & 3) << 4) | (col & 15);
          const long poff = (((row >> 5) * NJT + (col >> 4)) * 64 + lane2) * 8 + (row & 7);
          dpk_h[poff] = hh;
          dpk_l[poff] = ll;
        }
      }
    }
}

// ---------------- software grid barrier ----------------
__device__ __forceinline__ void gbar(u32* cnt, u32* gen, u32 nb) {
  __syncthreads();
  if (threadIdx.x == 0) {
    __threadfence();
    const u32 g = atomicAdd(gen, 0u);
    if (atomicAdd(cnt, 1u) == nb - 1u) {
      atomicExch(cnt, 0u);
      __threadfence();
      atomicAdd(gen, 1u);
    } else {
      while (atomicAdd(gen, 0u) == g) __builtin_amdgcn_s_sleep(4);
    }
    __threadfence();
  }
  __syncthreads();
}

// ---------------- phase C: boundary S-chain ----------------
// 128 blocks (32x32 tiles over [128,1024]). S_c = S_{c-1}*WL^T + e_c,
// read slot c-1 / write slot c of the stacked sS planes. 62 serial steps.
__global__ __launch_bounds__(256) void k_boundary(
    u16* sSh, u16* sSl,
    const u16* __restrict__ wlh, const u16* __restrict__ wll,
    const float* __restrict__ e, u32* cnt, u32* gen) {
  const int tile = blockIdx.x;
  const int tm = tile >> 5, tn = tile & 31;
  const int tid = threadIdx.x;
  const int l = tid & 63;
  const int w = tid >> 6;
  const int wr = w >> 1, wc = w & 1;
  const int row0 = tm * 32 + wr * 16;
  const int col0 = tn * 32 + wc * 16;
  const int jt = col0 >> 4;
#pragma unroll 1
  for (int c = 1; c < 63; ++c) {
    const u16* ah = sSh + (long)(c - 1) * NB * HD;
    const u16* al = sSl + (long)(c - 1) * NB * HD;
    f32x4 acc = (f32x4){0.f, 0.f, 0.f, 0.f};
#pragma unroll 4
    for (int ks = 0; ks < 32; ++ks) {
      const long aoff = (long)(row0 + (l & 15)) * HD + ks * 32 + (l >> 4) * 8;
      const s16x8 A = *(const s16x8*)(ah + aoff);
      const s16x8 A2 = *(const s16x8*)(al + aoff);
      const long boff = (((long)ks * NJT + jt) * 64 + l) * 8;
      const s16x8 B = *(const s16x8*)(wlh + boff);
      const s16x8 B2 = *(const s16x8*)(wll + boff);
      acc = MFMA16(A, B, acc);
      acc = MFMA16(A2, B, acc);
      acc = MFMA16(A, B2, acc);
    }
    const int crow = (l >> 4) * 4, ccol = l & 15;
    const int col = col0 + ccol;
    u16* dh = sSh + (long)c * NB * HD;
    u16* dl = sSl + (long)c * NB * HD;
#pragma unroll
    for (int r = 0; r < 4; ++r) {
      const int row = row0 + crow + r;
      const float v = acc[r] + e[((long)c * NB + row) * HD + col];
      u16 hh, ll; split2(v, hh, ll);
      dh[(long)row * HD + col] = hh;
      dl[(long)row * HD + col] = ll;
    }
    gbar(cnt, gen, 128u);
  }
}

// ---------------- phases B / D: per-chunk scan ----------------
// 256 blocks = 64 chunks x 4 row-groups of 32; 16 waves/block (4/SIMD).
// State as bf16 hi/lo planes in LDS (XOR-swizzled 16B blocks).
// EMIT=0: local scan, writes chunk-end e_c.  EMIT=1: true scan from Z_c,
// writes both output copies (NT).
template <int EMIT>
__global__ __launch_bounds__(1024) void k_scan(
    const float* proj, const float* __restrict__ initial,
    const u16* __restrict__ wph, const u16* __restrict__ wpl,
    const float* __restrict__ zbuf, float* __restrict__ ebuf,
    float* out1, float* out2) {
  __shared__ u16 sh[32 * HD];
  __shared__ u16 sl[32 * HD];
  const int b = blockIdx.x;
  const int c = b >> 2;
  const int g = b & 3;
  const int tid = threadIdx.x;
  const int l = tid & 63;
  const int w = tid >> 6;  // 0..15
  const long t0 = (long)c * LCH;
  const int ccol = l & 15;
  const int q = l >> 4;
  const int jt0 = w * 4;  // 4 col-tiles (64 cols) per wave
  const int akey = l & 7;
  const int rowoff0 = ccol * HD;
  const int rowoff1 = (16 + ccol) * HD;

  // Prefetch proj[t0] into acc-layout regs (step-1 accumulator init).
  float pn[2][4][4];
#pragma unroll
  for (int rt = 0; rt < 2; ++rt)
#pragma unroll
    for (int ct = 0; ct < 4; ++ct) {
      const int col = (jt0 + ct) * 16 + ccol;
#pragma unroll
      for (int r = 0; r < 4; ++r) {
        const int n = g * 32 + rt * 16 + q * 4 + r;
        pn[rt][ct][r] = ntl(proj + ((long)n * TS + t0) * HD + col);
      }
    }
  __syncthreads();  // pn loads drained before any out2 (== proj) writes below

  // Init state planes (+ for EMIT, write out[t0]).
  for (int i = tid; i < 32 * HD; i += 1024) {
    const int r = i >> 10;
    const int col = i & (HD - 1);
    const int n = g * 32 + r;
    float v;
    if (c == 0) {
      v = ntl(initial + (long)n * HD + col) + ntl(proj + ((long)n * TS) * HD + col);
    } else {
      if constexpr (EMIT) v = ntl(zbuf + ((long)c * NB + n) * HD + col);
      else                v = ntl(proj + ((long)n * TS + t0 - 1) * HD + col);
    }
    u16 hh, ll; split2(v, hh, ll);
    const int si = r * HD + ((((col >> 3) ^ (r & 7)) << 3) | (col & 7));
    sh[si] = hh; sl[si] = ll;
    if constexpr (EMIT) {
      const long o = ((long)n * TS + t0) * HD + col;
      nts(v, out1 + o); nts(v, out2 + o);
    }
  }
  __syncthreads();

  f32x4 acc[2][4];
#pragma unroll 1
  for (int step = 1; step < LCH; ++step) {
    const long t = t0 + step;
    // acc <- pn (proj[t-1])
#pragma unroll
    for (int rt = 0; rt < 2; ++rt)
#pragma unroll
      for (int ct = 0; ct < 4; ++ct) {
        acc[rt][ct][0] = pn[rt][ct][0];
        acc[rt][ct][1] = pn[rt][ct][1];
        acc[rt][ct][2] = pn[rt][ct][2];
        acc[rt][ct][3] = pn[rt][ct][3];
      }
    // Prefetch proj[t] for next step; hides under the MFMA loop. Safe vs the
    // EMIT out2[t] alias: the pre-write barrier drains vmcnt.
#pragma unroll
    for (int rt = 0; rt < 2; ++rt)
#pragma unroll
      for (int ct = 0; ct < 4; ++ct) {
        const int col = (jt0 + ct) * 16 + ccol;
#pragma unroll
        for (int r = 0; r < 4; ++r) {
          const int n = g * 32 + rt * 16 + q * 4 + r;
          pn[rt][ct][r] = ntl(proj + ((long)n * TS + t) * HD + col);
        }
      }
#pragma unroll 2
    for (int ks = 0; ks < 32; ++ks) {
      const int colpart = ((((ks << 2) | q) ^ akey) << 3);
      const s16x8 ah0 = *(const s16x8*)&sh[rowoff0 + colpart];
      const s16x8 al0 = *(const s16x8*)&sl[rowoff0 + colpart];
      const s16x8 ah1 = *(const s16x8*)&sh[rowoff1 + colpart];
      const s16x8 al1 = *(const s16x8*)&sl[rowoff1 + colpart];
#pragma unroll
      for (int ct = 0; ct < 4; ++ct) {
        const long boff = (((long)ks * NJT + jt0 + ct) * 64 + l) * 8;
        const s16x8 bh = *(const s16x8*)(wph + boff);
        const s16x8 bl = *(const s16x8*)(wpl + boff);
        acc[0][ct] = MFMA16(ah0, bh, acc[0][ct]);
        acc[0][ct] = MFMA16(al0, bh, acc[0][ct]);
        acc[0][ct] = MFMA16(ah0, bl, acc[0][ct]);
        acc[1][ct] = MFMA16(ah1, bh, acc[1][ct]);
        acc[1][ct] = MFMA16(al1, bh, acc[1][ct]);
        acc[1][ct] = MFMA16(ah1, bl, acc[1][ct]);
      }
    }
    __syncthreads();  // plane reads done; also drains the pn prefetch
    // Producer write-back: split once, store planes (+ NT emit).
#pragma unroll
    for (int rt = 0; rt < 2; ++rt)
#pragma unroll
      for (int ct = 0; ct < 4; ++ct) {
        const int colb = (jt0 + ct) * 16 + ccol;
        const int cb7 = colb & 7;
        const int cblk = colb >> 3;
#pragma unroll
        for (int r = 0; r < 4; ++r) {
          const int row = rt * 16 + q * 4 + r;
          const float v = acc[rt][ct][r];
          u16 hh, ll; split2(v, hh, ll);
          const int si = row * HD + (((cblk ^ (row & 7)) << 3) | cb7);
          sh[si] = hh; sl[si] = ll;
          if constexpr (EMIT) {
            const long o = ((long)(g * 32 + row) * TS + t) * HD + colb;
            nts(v, out1 + o); nts(v, out2 + o);
          }
        }
      }
    __syncthreads();
  }
  if constexpr (!EMIT) {
    for (int i = tid; i < 32 * HD; i += 1024) {
      const int r = i >> 10;
      const int col = i & (HD - 1);
      const int si = r * HD + ((((col >> 3) ^ (r & 7)) << 3) | (col & 7));
      const float v = bf2f(sh[si]) + bf2f(sl[si]);
      ebuf[((long)c * NB + g * 32 + r) * HD + col] = v;
    }
  }
}

// ---------------- host ----------------

extern "C" void kernel_launch(void* const* d_in, const int* in_sizes, int n_in,
                              void* d_out, int out_size, void* d_ws, size_t ws_size,
                              hipStream_t stream) {
  const float* x = (const float*)d_in[0];
  const float* w_ih = (const float*)d_in[1];
  const float* b_ih = (const float*)d_in[2];
  const float* w_hh = (const float*)d_in[3];
  const float* initial = (const float*)d_in[4];

  char* r1 = (char*)d_out;  // out copy 1: scratch until phase D
  float* out1 = (float*)d_out;
  float* proj = out1 + (long)NB * TS * HD;  // out copy 2: proj scratch
  float* out2 = proj;

  u16* xh = (u16*)(r1 + 0L);
  u16* xl = (u16*)(r1 + 67108864L);
  float* e = (float*)(r1 + 134217728L);
  u16* wt_rm_h = (u16*)(r1 + 167772160L);
  u16* wt_rm_l = (u16*)(r1 + 169869312L);
  u16* pw_rm_h[2] = {(u16*)(r1 + 171966464L), (u16*)(r1 + 176160768L)};
  u16* pw_rm_l[2] = {(u16*)(r1 + 174063616L), (u16*)(r1 + 178257920L)};
  u16* pw_pk_h[2] = {(u16*)(r1 + 180355072L), (u16*)(r1 + 184549376L)};
  u16* pw_pk_l[2] = {(u16*)(r1 + 182452224L), (u16*)(r1 + 186646528L)};
  u16* wih_h = (u16*)(r1 + 188743680L);
  u16* wih_l = (u16*)(r1 + 189005824L);
  u16* sSh = (u16*)(r1 + 192937984L);
  u16* sSl = (u16*)(r1 + 209715200L);

  char* wsb = (char*)d_ws;
  u16* wt_pk_h = (u16*)(wsb + 0L);
  u16* wt_pk_l = (u16*)(wsb + 2097152L);
  float* zbuf = (float*)(wsb + 4194304L);
  u32* cnt = (u32*)(wsb + 37748736L);
  u32* gen = cnt + 1;

  hipMemsetAsync(cnt, 0, 8, stream);

  // prep: split x, pack W^T matrices
  k_split_x<<<32768, 256, 0, stream>>>(x, xh, xl, (long)NB * TS * ID / 4);
  // Wt[k][j] = w_hh[j][k]  (sk=1, sj=HD)
  k_pack_b<<<512, 256, 0, stream>>>(w_hh, 1L, (long)HD, NJT, 32 * NJT * 64, wt_pk_h, wt_pk_l);
  // wihT[i][h] = w_ih[h][i]  (sk=1, sj=ID)
  k_pack_b<<<64, 256, 0, stream>>>(w_ih, 1L, (long)ID, NJT, 4 * NJT * 64, wih_h, wih_l);
  k_split_strided<<<4096, 256, 0, stream>>>(w_hh, 1L, (long)HD, HD, (long)HD * HD, wt_rm_h, wt_rm_l);

  // phase A: proj = x @ w_ih^T + b_ih
  dim3 gproj(2048, 8);
  k_gemm3<1, 4, 4><<<gproj, 256, 0, stream>>>(xh, xl, (long)ID, wih_h, wih_l, ID / 32,
                                              b_ih, proj, (long)HD, nullptr, nullptr, nullptr, nullptr);

  // W^L squaring chain (L=32 -> 5 squarings), fused epilogue writes rm+pack.
  const u16 *arh = wt_rm_h, *arl = wt_rm_l, *aph = wt_pk_h, *apl = wt_pk_l;
  dim3 g1616(16, 16);
  for (int i = 0; i < 5; ++i) {
    const int s = i & 1;
    k_gemm3<3, 2, 2><<<g1616, 256, 0, stream>>>(arh, arl, (long)HD, aph, apl, HD / 32,
                                                nullptr, nullptr, 0L,
                                                pw_rm_h[s], pw_rm_l[s], pw_pk_h[s], pw_pk_l[s]);
    arh = pw_rm_h[s]; arl = pw_rm_l[s]; aph = pw_pk_h[s]; apl = pw_pk_l[s];
  }

  // phase B: per-chunk local scans -> e_c
  k_scan<0><<<256, 1024, 0, stream>>>(proj, initial, wt_pk_h, wt_pk_l, nullptr, e, nullptr, nullptr);

  // split e_0 -> sS slot 0 (S_0 = e_0)
  k_split_strided<<<512, 256, 0, stream>>>(e, (long)HD, 1L, HD, (long)NB * HD, sSh, sSl);

  // phase C: serial S-chain (62 steps, software grid barrier over 128 blocks)
  k_boundary<<<128, 256, 0, stream>>>(sSh, sSl, aph, apl, e, cnt, gen);

  // Z-inits for phase D: Z_c = S_{c-1} * W^T + proj[:, c*L-1], c = 1..63
  dim3 gz(63, 8);
  k_gemm3<2, 4, 4><<<gz, 256, 0, stream>>>(sSh, sSl, (long)HD, wt_pk_h, wt_pk_l, HD / 32,
                                           proj, zbuf, 0L, nullptr, nullptr, nullptr, nullptr);

  // phase D: emit all hidden states (both output copies)
  k_scan<1><<<256, 1024, 0, stream>>>(proj, initial, wt_pk_h, wt_pk_l, zbuf, nullptr, out1, out2);
}